// Round 1
// baseline (531.622 us; speedup 1.0000x reference)
//
#include <hip/hip_runtime.h>
#include <cstdint>
#include <cstddef>

// GNNEncoder: 2x (edge-MLP GNN layer) + mean pool + MLP head.
// Key algebra: per-edge MLP layer decomposes into node-level GEMMs:
//   A = x @ W1[:128], B = x @ W1[128:]            (node GEMM, fused as [128,256])
//   hidden_e = relu(A[dst] + b1 + B[src])          (edge elementwise, CSR gather)
//   segsum(hidden@W2 + b2) = segsum(hidden)@W2 + deg*b2   (node GEMM)

static constexpr int GRAPHS = 64;

// ---------------- CSR build ----------------
__global__ __launch_bounds__(256) void zero_k(int* __restrict__ p, int n) {
    int i = blockIdx.x * 256 + threadIdx.x;
    if (i < n) p[i] = 0;
}

__global__ __launch_bounds__(256) void hist_k(const int* __restrict__ dst, int* __restrict__ deg, int E) {
    int i = blockIdx.x * 256 + threadIdx.x;
    if (i < E) atomicAdd(&deg[dst[i]], 1);
}

// block scans 1024 elements (4/thread), writes per-block exclusive scan + block total
__global__ __launch_bounds__(256) void scan1_k(const int* __restrict__ deg, int* __restrict__ rp,
                                               int* __restrict__ part, int n) {
    __shared__ int ts[256];
    int b = blockIdx.x, t = threadIdx.x;
    int base = b * 1024 + t * 4;
    int v0 = (base + 0 < n) ? deg[base + 0] : 0;
    int v1 = (base + 1 < n) ? deg[base + 1] : 0;
    int v2 = (base + 2 < n) ? deg[base + 2] : 0;
    int v3 = (base + 3 < n) ? deg[base + 3] : 0;
    int l0 = v0, l1 = l0 + v1, l2 = l1 + v2, l3 = l2 + v3;
    ts[t] = l3;
    __syncthreads();
    for (int off = 1; off < 256; off <<= 1) {
        int x = (t >= off) ? ts[t - off] : 0;
        __syncthreads();
        ts[t] += x;
        __syncthreads();
    }
    int ex = ts[t] - l3;  // exclusive offset of this thread within block
    if (base + 0 < n) rp[base + 0] = ex;
    if (base + 1 < n) rp[base + 1] = ex + l0;
    if (base + 2 < n) rp[base + 2] = ex + l1;
    if (base + 3 < n) rp[base + 3] = ex + l2;
    if (t == 255) part[b] = ts[255];
}

__global__ void scan2_k(int* __restrict__ part, int nb) {
    if (threadIdx.x == 0 && blockIdx.x == 0) {
        int s = 0;
        for (int i = 0; i < nb; ++i) { int v = part[i]; part[i] = s; s += v; }
        part[nb] = s;
    }
}

__global__ __launch_bounds__(256) void scan3_k(int* __restrict__ rp, int* __restrict__ cursor,
                                               const int* __restrict__ part, int n, int nb) {
    int i = blockIdx.x * 256 + threadIdx.x;
    if (i < n) {
        int v = rp[i] + part[i >> 10];
        rp[i] = v;
        cursor[i] = v;
    } else if (i == n) {
        rp[n] = part[nb];
    }
}

__global__ __launch_bounds__(256) void fill_k(const int* __restrict__ src, const int* __restrict__ dst,
                                              int* __restrict__ cursor, int* __restrict__ col, int E) {
    int i = blockIdx.x * 256 + threadIdx.x;
    if (i < E) {
        int d = dst[i];
        int p = atomicAdd(&cursor[d], 1);
        col[p] = src[i];
    }
}

// ---------------- weight repack: w[256][128] -> wc[128][256] (dst cols | src cols) ----------------
__global__ __launch_bounds__(256) void repack_k(const float* __restrict__ w, float* __restrict__ wc) {
    int i = blockIdx.x * 256 + threadIdx.x;  // 128*256 = 32768
    int k = i >> 8;
    int j = i & 255;
    wc[i] = (j < 128) ? w[k * 128 + j] : w[(128 + k) * 128 + (j - 128)];
}

// ---------------- GEMM: Y[M][NOUT] = X[M][128] @ W[128][NOUT] (+bias*(deg?)) (relu?) ----------------
template <int NOUT, bool RELU, bool DEGBIAS>
__global__ __launch_bounds__(256) void gemm_k(const float* __restrict__ X, int ldx,
                                              const float* __restrict__ W,
                                              const float* __restrict__ bias,
                                              const int* __restrict__ rp,
                                              float* __restrict__ Y, int ldy, int M) {
    constexpr int MT = 32, K = 128, CPT = 4;
    constexpr int NCG = NOUT / CPT;
    constexpr int RPT = MT * NOUT / (256 * CPT);  // 8 for NOUT=256, 4 for NOUT=128
    __shared__ float Xs[MT][K + 4];
    int t = threadIdx.x;
    int m0 = blockIdx.x * MT;
#pragma unroll
    for (int i = 0; i < 4; ++i) {
        int idx = t + i * 256;
        int r = idx >> 5, c4 = idx & 31;
        float4 v = *reinterpret_cast<const float4*>(X + (size_t)(m0 + r) * ldx + c4 * 4);
        *reinterpret_cast<float4*>(&Xs[r][c4 * 4]) = v;
    }
    __syncthreads();
    int cg = t % NCG, rg = t / NCG;
    int c0 = cg * CPT, r0 = rg * RPT;
    float acc[RPT][CPT];
#pragma unroll
    for (int i = 0; i < RPT; ++i)
#pragma unroll
        for (int j = 0; j < CPT; ++j) acc[i][j] = 0.f;
#pragma unroll 4
    for (int k = 0; k < K; ++k) {
        float4 w = *reinterpret_cast<const float4*>(W + k * NOUT + c0);
#pragma unroll
        for (int i = 0; i < RPT; ++i) {
            float xv = Xs[r0 + i][k];
            acc[i][0] += xv * w.x;
            acc[i][1] += xv * w.y;
            acc[i][2] += xv * w.z;
            acc[i][3] += xv * w.w;
        }
    }
#pragma unroll
    for (int i = 0; i < RPT; ++i) {
        int r = m0 + r0 + i;
        float4 o = make_float4(acc[i][0], acc[i][1], acc[i][2], acc[i][3]);
        if (bias != nullptr) {
            float s = 1.f;
            if (DEGBIAS) s = (float)(rp[r + 1] - rp[r]);
            o.x += s * bias[c0 + 0];
            o.y += s * bias[c0 + 1];
            o.z += s * bias[c0 + 2];
            o.w += s * bias[c0 + 3];
        }
        if (RELU) {
            o.x = fmaxf(o.x, 0.f);
            o.y = fmaxf(o.y, 0.f);
            o.z = fmaxf(o.z, 0.f);
            o.w = fmaxf(o.w, 0.f);
        }
        *reinterpret_cast<float4*>(Y + (size_t)r * ldy + c0) = o;
    }
}

// ---------------- edge aggregation (in place: Hagg overwrites A-half of AB) ----------------
// AB layout: row n = [A[n] (128) | B[n] (128)], stride 256.
// wave (64 lanes) per node, float2 per lane. Writes Hagg into AB[n][0:128].
__global__ __launch_bounds__(256) void agg_k(float* __restrict__ AB, const float* __restrict__ b1,
                                             const int* __restrict__ rp, const int* __restrict__ col,
                                             int M) {
    int wave = threadIdx.x >> 6;
    int lane = threadIdx.x & 63;
    int n = blockIdx.x * 4 + wave;
    float2 a = *reinterpret_cast<const float2*>(AB + (size_t)n * 256 + lane * 2);
    float2 bb = *reinterpret_cast<const float2*>(b1 + lane * 2);
    a.x += bb.x;
    a.y += bb.y;
    float2 acc = make_float2(0.f, 0.f);
    int e0 = rp[n], e1 = rp[n + 1];
    for (int e = e0; e < e1; ++e) {
        int s = col[e];
        float2 bv = *reinterpret_cast<const float2*>(AB + (size_t)s * 256 + 128 + lane * 2);
        acc.x += fmaxf(a.x + bv.x, 0.f);
        acc.y += fmaxf(a.y + bv.y, 0.f);
    }
    *reinterpret_cast<float2*>(AB + (size_t)n * 256 + lane * 2) = acc;
}

// ---------------- pooling ----------------
__global__ void gstart_k(const int* __restrict__ batch, int N, int G, int* __restrict__ gs) {
    int t = threadIdx.x;
    if (t > G) return;
    int lo = 0, hi = N;
    while (lo < hi) {
        int mid = (lo + hi) >> 1;
        if (batch[mid] < t) lo = mid + 1;
        else hi = mid;
    }
    gs[t] = lo;
}

__global__ __launch_bounds__(128) void pool_k(const float* __restrict__ H, const int* __restrict__ gs,
                                              float* __restrict__ pooled) {
    int g = blockIdx.x, f = threadIdx.x;
    int s = gs[g], e = gs[g + 1];
    float acc = 0.f;
    for (int n = s; n < e; ++n) acc += H[(size_t)n * 128 + f];
    float c = (float)(e - s);
    pooled[g * 128 + f] = acc / fmaxf(c, 1.f);
}

// ---------------- head MLP: relu(pooled@wm1+bm1)@wm2+bm2 -> out[64][512] ----------------
__global__ __launch_bounds__(128) void head_k(const float* __restrict__ pooled,
                                              const float* __restrict__ wm1, const float* __restrict__ bm1,
                                              const float* __restrict__ wm2, const float* __restrict__ bm2,
                                              float* __restrict__ out) {
    __shared__ float p[128];
    __shared__ float h[128];
    int g = blockIdx.x, t = threadIdx.x;
    p[t] = pooled[g * 128 + t];
    __syncthreads();
    float a = bm1[t];
    for (int k = 0; k < 128; ++k) a += p[k] * wm1[k * 128 + t];
    h[t] = fmaxf(a, 0.f);
    __syncthreads();
    float acc[4];
#pragma unroll
    for (int j = 0; j < 4; ++j) acc[j] = bm2[j * 128 + t];
    for (int k = 0; k < 128; ++k) {
        float hv = h[k];
#pragma unroll
        for (int j = 0; j < 4; ++j) acc[j] += hv * wm2[k * 512 + j * 128 + t];
    }
#pragma unroll
    for (int j = 0; j < 4; ++j) out[(size_t)g * 512 + j * 128 + t] = acc[j];
}

extern "C" void kernel_launch(void* const* d_in, const int* in_sizes, int n_in,
                              void* d_out, int out_size, void* d_ws, size_t ws_size,
                              hipStream_t stream) {
    const float* x = (const float*)d_in[0];
    const int* ei = (const int*)d_in[1];
    const int* batch = (const int*)d_in[2];
    const float* w1_1 = (const float*)d_in[3];
    const float* b1_1 = (const float*)d_in[4];
    const float* w1_2 = (const float*)d_in[5];
    const float* b1_2 = (const float*)d_in[6];
    const float* w2_1 = (const float*)d_in[7];
    const float* b2_1 = (const float*)d_in[8];
    const float* w2_2 = (const float*)d_in[9];
    const float* b2_2 = (const float*)d_in[10];
    const float* wm1 = (const float*)d_in[11];
    const float* bm1 = (const float*)d_in[12];
    const float* wm2 = (const float*)d_in[13];
    const float* bm2 = (const float*)d_in[14];

    const int E = in_sizes[1] / 2;
    const int M = in_sizes[0] / 128;
    const int* srcp = ei;
    const int* dstp = ei + E;

    char* ws = (char*)d_ws;
    size_t off = 0;
    auto alloc = [&](size_t bytes) -> void* {
        void* p = ws + off;
        off += (bytes + 255) & ~(size_t)255;
        return p;
    };
    float* AB = (float*)alloc((size_t)M * 256 * 4);      // [M][256] : A|B, Hagg overwrites A-half
    float* H = (float*)alloc((size_t)M * 128 * 4);       // layer output
    int* rp = (int*)alloc((size_t)(M + 1) * 4);          // CSR row_ptr over dst
    int* cursor = (int*)alloc((size_t)M * 4);            // also used as deg
    int* col = (int*)alloc((size_t)E * 4);               // CSR col (src ids)
    int* part = (int*)alloc(64 * 4);                     // scan partials
    int* gs = (int*)alloc((GRAPHS + 1) * 4);             // graph boundaries
    float* pooled = (float*)alloc(GRAPHS * 128 * 4);
    float* wc = (float*)alloc(128 * 256 * 4);            // repacked [128][256] weights

    const int nb = (M + 1023) / 1024;

    // CSR build over dst (shared by both layers)
    zero_k<<<(M + 255) / 256, 256, 0, stream>>>(cursor, M);
    hist_k<<<(E + 255) / 256, 256, 0, stream>>>(dstp, cursor, E);
    scan1_k<<<nb, 256, 0, stream>>>(cursor, rp, part, M);
    scan2_k<<<1, 64, 0, stream>>>(part, nb);
    scan3_k<<<(M + 256) / 256, 256, 0, stream>>>(rp, cursor, part, M, nb);
    fill_k<<<(E + 255) / 256, 256, 0, stream>>>(srcp, dstp, cursor, col, E);

    // layer 1
    repack_k<<<128, 256, 0, stream>>>(w1_1, wc);
    gemm_k<256, false, false><<<M / 32, 256, 0, stream>>>(x, 128, wc, nullptr, nullptr, AB, 256, M);
    agg_k<<<M / 4, 256, 0, stream>>>(AB, b1_1, rp, col, M);
    gemm_k<128, true, true><<<M / 32, 256, 0, stream>>>(AB, 256, w1_2, b1_2, rp, H, 128, M);

    // layer 2
    repack_k<<<128, 256, 0, stream>>>(w2_1, wc);
    gemm_k<256, false, false><<<M / 32, 256, 0, stream>>>(H, 128, wc, nullptr, nullptr, AB, 256, M);
    agg_k<<<M / 4, 256, 0, stream>>>(AB, b2_1, rp, col, M);
    gemm_k<128, true, true><<<M / 32, 256, 0, stream>>>(AB, 256, w2_2, b2_2, rp, H, 128, M);

    // pool + head
    gstart_k<<<1, 128, 0, stream>>>(batch, M, GRAPHS, gs);
    pool_k<<<GRAPHS, 128, 0, stream>>>(H, gs, pooled);
    head_k<<<GRAPHS, 128, 0, stream>>>(pooled, wm1, bm1, wm2, bm2, (float*)d_out);
}

// Round 2
// 401.556 us; speedup vs baseline: 1.3239x; 1.3239x over previous
//
#include <hip/hip_runtime.h>
#include <cstdint>
#include <cstddef>

// GNNEncoder: 2x (edge-MLP GNN layer) + mean pool + MLP head.
// Key algebra: per-edge MLP layer decomposes into node-level GEMMs:
//   A = x @ W1[:128], B = x @ W1[128:]            (node GEMM, fused as [128,256])
//   hidden_e = relu(A[dst] + b1 + B[src])          (edge elementwise, CSR gather)
//   segsum(hidden@W2 + b2) = segsum(hidden)@W2 + deg*b2   (node GEMM)

static constexpr int GRAPHS = 64;

// ---------------- CSR build ----------------
__global__ __launch_bounds__(256) void zero_k(int* __restrict__ p, int n) {
    int i = blockIdx.x * 256 + threadIdx.x;
    if (i < n) p[i] = 0;
}

__global__ __launch_bounds__(256) void hist_k(const int* __restrict__ dst, int* __restrict__ deg, int E) {
    int i = blockIdx.x * 256 + threadIdx.x;
    if (i < E) atomicAdd(&deg[dst[i]], 1);
}

// block scans 1024 elements (4/thread), writes per-block exclusive scan + block total
__global__ __launch_bounds__(256) void scan1_k(const int* __restrict__ deg, int* __restrict__ rp,
                                               int* __restrict__ part, int n) {
    __shared__ int ts[256];
    int b = blockIdx.x, t = threadIdx.x;
    int base = b * 1024 + t * 4;
    int v0 = (base + 0 < n) ? deg[base + 0] : 0;
    int v1 = (base + 1 < n) ? deg[base + 1] : 0;
    int v2 = (base + 2 < n) ? deg[base + 2] : 0;
    int v3 = (base + 3 < n) ? deg[base + 3] : 0;
    int l0 = v0, l1 = l0 + v1, l2 = l1 + v2, l3 = l2 + v3;
    ts[t] = l3;
    __syncthreads();
    for (int off = 1; off < 256; off <<= 1) {
        int x = (t >= off) ? ts[t - off] : 0;
        __syncthreads();
        ts[t] += x;
        __syncthreads();
    }
    int ex = ts[t] - l3;  // exclusive offset of this thread within block
    if (base + 0 < n) rp[base + 0] = ex;
    if (base + 1 < n) rp[base + 1] = ex + l0;
    if (base + 2 < n) rp[base + 2] = ex + l1;
    if (base + 3 < n) rp[base + 3] = ex + l2;
    if (t == 255) part[b] = ts[255];
}

__global__ void scan2_k(int* __restrict__ part, int nb) {
    if (threadIdx.x == 0 && blockIdx.x == 0) {
        int s = 0;
        for (int i = 0; i < nb; ++i) { int v = part[i]; part[i] = s; s += v; }
        part[nb] = s;
    }
}

__global__ __launch_bounds__(256) void scan3_k(int* __restrict__ rp, int* __restrict__ cursor,
                                               const int* __restrict__ part, int n, int nb) {
    int i = blockIdx.x * 256 + threadIdx.x;
    if (i < n) {
        int v = rp[i] + part[i >> 10];
        rp[i] = v;
        cursor[i] = v;
    } else if (i == n) {
        rp[n] = part[nb];
    }
}

__global__ __launch_bounds__(256) void fill_k(const int* __restrict__ src, const int* __restrict__ dst,
                                              int* __restrict__ cursor, int* __restrict__ col, int E) {
    int i = blockIdx.x * 256 + threadIdx.x;
    if (i < E) {
        int d = dst[i];
        int p = atomicAdd(&cursor[d], 1);
        col[p] = src[i];
    }
}

// ---------------- weight repack: w[256][128] -> wc[128][256] (dst cols | src cols) ----------------
__global__ __launch_bounds__(256) void repack_k(const float* __restrict__ w, float* __restrict__ wc) {
    int i = blockIdx.x * 256 + threadIdx.x;  // 128*256 = 32768
    int k = i >> 8;
    int j = i & 255;
    wc[i] = (j < 128) ? w[k * 128 + j] : w[(128 + k) * 128 + (j - 128)];
}

// ---------------- GEMM: Y[M][NOUT] = X[M][128] @ W[128][NOUT] (+bias*(deg?)) (relu?) ----------------
template <int NOUT, bool RELU, bool DEGBIAS>
__global__ __launch_bounds__(256) void gemm_k(const float* __restrict__ X, int ldx,
                                              const float* __restrict__ W,
                                              const float* __restrict__ bias,
                                              const int* __restrict__ rp,
                                              float* __restrict__ Y, int ldy, int M) {
    constexpr int MT = 32, K = 128, CPT = 4;
    constexpr int NCG = NOUT / CPT;
    constexpr int RPT = MT * NOUT / (256 * CPT);  // 8 for NOUT=256, 4 for NOUT=128
    __shared__ float Xs[MT][K + 4];
    int t = threadIdx.x;
    int m0 = blockIdx.x * MT;
#pragma unroll
    for (int i = 0; i < 4; ++i) {
        int idx = t + i * 256;
        int r = idx >> 5, c4 = idx & 31;
        float4 v = *reinterpret_cast<const float4*>(X + (size_t)(m0 + r) * ldx + c4 * 4);
        *reinterpret_cast<float4*>(&Xs[r][c4 * 4]) = v;
    }
    __syncthreads();
    int cg = t % NCG, rg = t / NCG;
    int c0 = cg * CPT, r0 = rg * RPT;
    float acc[RPT][CPT];
#pragma unroll
    for (int i = 0; i < RPT; ++i)
#pragma unroll
        for (int j = 0; j < CPT; ++j) acc[i][j] = 0.f;
#pragma unroll 4
    for (int k = 0; k < K; ++k) {
        float4 w = *reinterpret_cast<const float4*>(W + k * NOUT + c0);
#pragma unroll
        for (int i = 0; i < RPT; ++i) {
            float xv = Xs[r0 + i][k];
            acc[i][0] += xv * w.x;
            acc[i][1] += xv * w.y;
            acc[i][2] += xv * w.z;
            acc[i][3] += xv * w.w;
        }
    }
#pragma unroll
    for (int i = 0; i < RPT; ++i) {
        int r = m0 + r0 + i;
        float4 o = make_float4(acc[i][0], acc[i][1], acc[i][2], acc[i][3]);
        if (bias != nullptr) {
            float s = 1.f;
            if (DEGBIAS) s = (float)(rp[r + 1] - rp[r]);
            o.x += s * bias[c0 + 0];
            o.y += s * bias[c0 + 1];
            o.z += s * bias[c0 + 2];
            o.w += s * bias[c0 + 3];
        }
        if (RELU) {
            o.x = fmaxf(o.x, 0.f);
            o.y = fmaxf(o.y, 0.f);
            o.z = fmaxf(o.z, 0.f);
            o.w = fmaxf(o.w, 0.f);
        }
        *reinterpret_cast<float4*>(Y + (size_t)r * ldy + c0) = o;
    }
}

// ---------------- edge aggregation (in place: Hagg overwrites A-half of AB) ----------------
// AB layout: row n = [A[n] (128) | B[n] (128)], stride 256.
// wave (64 lanes) per node, float2 per lane. Writes Hagg into AB[n][0:128].
__global__ __launch_bounds__(256) void agg_k(float* __restrict__ AB, const float* __restrict__ b1,
                                             const int* __restrict__ rp, const int* __restrict__ col,
                                             int M) {
    int wave = threadIdx.x >> 6;
    int lane = threadIdx.x & 63;
    int n = blockIdx.x * 4 + wave;
    float2 a = *reinterpret_cast<const float2*>(AB + (size_t)n * 256 + lane * 2);
    float2 bb = *reinterpret_cast<const float2*>(b1 + lane * 2);
    a.x += bb.x;
    a.y += bb.y;
    float2 acc = make_float2(0.f, 0.f);
    int e0 = rp[n], e1 = rp[n + 1];
    for (int e = e0; e < e1; ++e) {
        int s = col[e];
        float2 bv = *reinterpret_cast<const float2*>(AB + (size_t)s * 256 + 128 + lane * 2);
        acc.x += fmaxf(a.x + bv.x, 0.f);
        acc.y += fmaxf(a.y + bv.y, 0.f);
    }
    *reinterpret_cast<float2*>(AB + (size_t)n * 256 + lane * 2) = acc;
}

// ---------------- pooling (node-parallel, sorted batch, atomic flush at graph boundaries) ----
__global__ __launch_bounds__(128) void pool_k(const float* __restrict__ H, const int* __restrict__ batch,
                                              float* __restrict__ psum, int M, int nblk) {
    int f = threadIdx.x;
    int chunk = (M + nblk - 1) / nblk;
    int n0 = blockIdx.x * chunk;
    int n1 = n0 + chunk;
    if (n1 > M) n1 = M;
    if (n0 >= n1) return;
    int g = batch[n0];
    float acc = 0.f;
    for (int n = n0; n < n1; ++n) {
        int bg = batch[n];
        if (bg != g) {
            atomicAdd(&psum[g * 128 + f], acc);
            acc = 0.f;
            g = bg;
        }
        acc += H[(size_t)n * 128 + f];
    }
    atomicAdd(&psum[g * 128 + f], acc);
}

// ---------------- graph boundaries (for counts) ----------------
__global__ void gstart_k(const int* __restrict__ batch, int N, int G, int* __restrict__ gs) {
    int t = threadIdx.x;
    if (t > G) return;
    int lo = 0, hi = N;
    while (lo < hi) {
        int mid = (lo + hi) >> 1;
        if (batch[mid] < t) lo = mid + 1;
        else hi = mid;
    }
    gs[t] = lo;
}

// ---------------- head MLP: relu((psum/cnt)@wm1+bm1)@wm2+bm2 -> out[64][512] ----------------
__global__ __launch_bounds__(128) void head_k(const float* __restrict__ psum,
                                              const int* __restrict__ gs,
                                              const float* __restrict__ wm1, const float* __restrict__ bm1,
                                              const float* __restrict__ wm2, const float* __restrict__ bm2,
                                              float* __restrict__ out) {
    __shared__ float p[128];
    __shared__ float h[128];
    int g = blockIdx.x, t = threadIdx.x;
    int cnt = gs[g + 1] - gs[g];
    float rcp = 1.0f / (float)(cnt > 0 ? cnt : 1);
    p[t] = psum[g * 128 + t] * rcp;
    __syncthreads();
    float a = bm1[t];
    for (int k = 0; k < 128; ++k) a += p[k] * wm1[k * 128 + t];
    h[t] = fmaxf(a, 0.f);
    __syncthreads();
    float acc[4];
#pragma unroll
    for (int j = 0; j < 4; ++j) acc[j] = bm2[j * 128 + t];
    for (int k = 0; k < 128; ++k) {
        float hv = h[k];
#pragma unroll
        for (int j = 0; j < 4; ++j) acc[j] += hv * wm2[k * 512 + j * 128 + t];
    }
#pragma unroll
    for (int j = 0; j < 4; ++j) out[(size_t)g * 512 + j * 128 + t] = acc[j];
}

extern "C" void kernel_launch(void* const* d_in, const int* in_sizes, int n_in,
                              void* d_out, int out_size, void* d_ws, size_t ws_size,
                              hipStream_t stream) {
    const float* x = (const float*)d_in[0];
    const int* ei = (const int*)d_in[1];
    const int* batch = (const int*)d_in[2];
    const float* w1_1 = (const float*)d_in[3];
    const float* b1_1 = (const float*)d_in[4];
    const float* w1_2 = (const float*)d_in[5];
    const float* b1_2 = (const float*)d_in[6];
    const float* w2_1 = (const float*)d_in[7];
    const float* b2_1 = (const float*)d_in[8];
    const float* w2_2 = (const float*)d_in[9];
    const float* b2_2 = (const float*)d_in[10];
    const float* wm1 = (const float*)d_in[11];
    const float* bm1 = (const float*)d_in[12];
    const float* wm2 = (const float*)d_in[13];
    const float* bm2 = (const float*)d_in[14];

    const int E = in_sizes[1] / 2;
    const int M = in_sizes[0] / 128;
    const int* srcp = ei;
    const int* dstp = ei + E;

    char* ws = (char*)d_ws;
    size_t off = 0;
    auto alloc = [&](size_t bytes) -> void* {
        void* p = ws + off;
        off += (bytes + 255) & ~(size_t)255;
        return p;
    };
    float* AB = (float*)alloc((size_t)M * 256 * 4);      // [M][256] : A|B, Hagg overwrites A-half
    float* H = (float*)alloc((size_t)M * 128 * 4);       // layer output
    int* rp = (int*)alloc((size_t)(M + 1) * 4);          // CSR row_ptr over dst
    int* cursor = (int*)alloc((size_t)M * 4);            // also used as deg
    int* col = (int*)alloc((size_t)E * 4);               // CSR col (src ids)
    int* part = (int*)alloc(64 * 4);                     // scan partials
    int* gs = (int*)alloc((GRAPHS + 1) * 4);             // graph boundaries
    float* psum = (float*)alloc(GRAPHS * 128 * 4);       // pooled sums
    float* wc = (float*)alloc(128 * 256 * 4);            // repacked [128][256] weights

    const int nb = (M + 1023) / 1024;

    // CSR build over dst (shared by both layers)
    zero_k<<<(M + 255) / 256, 256, 0, stream>>>(cursor, M);
    hist_k<<<(E + 255) / 256, 256, 0, stream>>>(dstp, cursor, E);
    scan1_k<<<nb, 256, 0, stream>>>(cursor, rp, part, M);
    scan2_k<<<1, 64, 0, stream>>>(part, nb);
    scan3_k<<<(M + 256) / 256, 256, 0, stream>>>(rp, cursor, part, M, nb);
    fill_k<<<(E + 255) / 256, 256, 0, stream>>>(srcp, dstp, cursor, col, E);

    // layer 1
    repack_k<<<128, 256, 0, stream>>>(w1_1, wc);
    gemm_k<256, false, false><<<M / 32, 256, 0, stream>>>(x, 128, wc, nullptr, nullptr, AB, 256, M);
    agg_k<<<M / 4, 256, 0, stream>>>(AB, b1_1, rp, col, M);
    gemm_k<128, true, true><<<M / 32, 256, 0, stream>>>(AB, 256, w1_2, b1_2, rp, H, 128, M);

    // layer 2
    repack_k<<<128, 256, 0, stream>>>(w2_1, wc);
    gemm_k<256, false, false><<<M / 32, 256, 0, stream>>>(H, 128, wc, nullptr, nullptr, AB, 256, M);
    agg_k<<<M / 4, 256, 0, stream>>>(AB, b2_1, rp, col, M);
    gemm_k<128, true, true><<<M / 32, 256, 0, stream>>>(AB, 256, w2_2, b2_2, rp, H, 128, M);

    // pool + head
    zero_k<<<(GRAPHS * 128 + 255) / 256, 256, 0, stream>>>((int*)psum, GRAPHS * 128);
    gstart_k<<<1, 128, 0, stream>>>(batch, M, GRAPHS, gs);
    {
        const int nblk = 512;
        pool_k<<<nblk, 128, 0, stream>>>(H, batch, psum, M, nblk);
    }
    head_k<<<GRAPHS, 128, 0, stream>>>(psum, gs, wm1, bm1, wm2, bm2, (float*)d_out);
}

// Round 3
// 362.122 us; speedup vs baseline: 1.4681x; 1.1089x over previous
//
#include <hip/hip_runtime.h>
#include <cstdint>
#include <cstddef>

// GNNEncoder: 2x (edge-MLP GNN layer) + mean pool + MLP head. bf16 node pipeline.
//   AB = [A|B] = xb @ [W1a|W1b] + [b1|0]      (MFMA bf16 GEMM, bf16 out)
//   Hagg[n] = sum_{e: dst=n} relu(A[n] + B[src_e])   (bf16 gather, f32 accum)
//   H = relu(Hagg @ W2 + deg*b2)               (MFMA bf16 GEMM)
// mean-pool over ~625 nodes/graph suppresses bf16 noise ~25x before fp32 head.

static constexpr int GRAPHS = 64;

using bf16x8 = __attribute__((ext_vector_type(8))) short;
using f32x4 = __attribute__((ext_vector_type(4))) float;

__device__ inline float bf2f(uint u) { return __builtin_bit_cast(float, u << 16); }
__device__ inline float bf2f_hi(uint u) { return __builtin_bit_cast(float, u & 0xffff0000u); }
__device__ inline ushort f2bf(float f) {
    uint u = __builtin_bit_cast(uint, f);
    return (ushort)((u + 0x7fffu + ((u >> 16) & 1u)) >> 16);
}

// ---------------- CSR build ----------------
__global__ __launch_bounds__(256) void zero_k(int* __restrict__ p, int n) {
    int i = blockIdx.x * 256 + threadIdx.x;
    if (i < n) p[i] = 0;
}

__global__ __launch_bounds__(256) void hist_k(const int* __restrict__ dst, int* __restrict__ deg, int E) {
    int i = blockIdx.x * 256 + threadIdx.x;
    if (i < E) atomicAdd(&deg[dst[i]], 1);
}

__global__ __launch_bounds__(256) void scan1_k(const int* __restrict__ deg, int* __restrict__ rp,
                                               int* __restrict__ part, int n) {
    __shared__ int ts[256];
    int b = blockIdx.x, t = threadIdx.x;
    int base = b * 1024 + t * 4;
    int v0 = (base + 0 < n) ? deg[base + 0] : 0;
    int v1 = (base + 1 < n) ? deg[base + 1] : 0;
    int v2 = (base + 2 < n) ? deg[base + 2] : 0;
    int v3 = (base + 3 < n) ? deg[base + 3] : 0;
    int l0 = v0, l1 = l0 + v1, l2 = l1 + v2, l3 = l2 + v3;
    ts[t] = l3;
    __syncthreads();
    for (int off = 1; off < 256; off <<= 1) {
        int x = (t >= off) ? ts[t - off] : 0;
        __syncthreads();
        ts[t] += x;
        __syncthreads();
    }
    int ex = ts[t] - l3;
    if (base + 0 < n) rp[base + 0] = ex;
    if (base + 1 < n) rp[base + 1] = ex + l0;
    if (base + 2 < n) rp[base + 2] = ex + l1;
    if (base + 3 < n) rp[base + 3] = ex + l2;
    if (t == 255) part[b] = ts[255];
}

__global__ void scan2_k(int* __restrict__ part, int nb) {
    if (threadIdx.x == 0 && blockIdx.x == 0) {
        int s = 0;
        for (int i = 0; i < nb; ++i) { int v = part[i]; part[i] = s; s += v; }
        part[nb] = s;
    }
}

__global__ __launch_bounds__(256) void scan3_k(int* __restrict__ rp, int* __restrict__ cursor,
                                               const int* __restrict__ part, int n, int nb) {
    int i = blockIdx.x * 256 + threadIdx.x;
    if (i < n) {
        int v = rp[i] + part[i >> 10];
        rp[i] = v;
        cursor[i] = v;
    } else if (i == n) {
        rp[n] = part[nb];
    }
}

__global__ __launch_bounds__(256) void fill_k(const int* __restrict__ src, const int* __restrict__ dst,
                                              int* __restrict__ cursor, int* __restrict__ col, int E) {
    int i = blockIdx.x * 256 + threadIdx.x;
    if (i < E) {
        int d = dst[i];
        int p = atomicAdd(&cursor[d], 1);
        col[p] = src[i];
    }
}

// ---------------- x -> bf16 ----------------
__global__ __launch_bounds__(256) void cast_k(const float* __restrict__ x, ushort* __restrict__ xb, int n4) {
    int i = blockIdx.x * 256 + threadIdx.x;  // one float4 -> 4 bf16 per thread
    if (i >= n4) return;
    float4 v = *reinterpret_cast<const float4*>(x + (size_t)i * 4);
    ushort4 o;
    o.x = f2bf(v.x); o.y = f2bf(v.y); o.z = f2bf(v.z); o.w = f2bf(v.w);
    *reinterpret_cast<ushort4*>(xb + (size_t)i * 4) = o;
}

// ---------------- weight prep: transposed bf16 weights + fused biases ----------------
// wt1a[256][128]: wt1a[j][k] = j<128 ? w1_1[k][j] : w1_1[128+k][j-128]   (layer1 fused)
// wt1b same from w2_1 (layer2). wt2a[128][128]: w1_2[k][j] transposed; wt2b from w2_2.
// b256_1 = [b1_1 | 0], b256_2 = [b2_1 | 0].
__global__ __launch_bounds__(256) void prep_k(const float* __restrict__ w1_1, const float* __restrict__ w2_1,
                                              const float* __restrict__ w1_2, const float* __restrict__ w2_2,
                                              const float* __restrict__ b1_1, const float* __restrict__ b2_1,
                                              ushort* __restrict__ wt1a, ushort* __restrict__ wt1b,
                                              ushort* __restrict__ wt2a, ushort* __restrict__ wt2b,
                                              float* __restrict__ b256_1, float* __restrict__ b256_2) {
    int i = blockIdx.x * 256 + threadIdx.x;
    if (i < 32768) {
        int j = i >> 7, k = i & 127;
        float v = (j < 128) ? w1_1[k * 128 + j] : w1_1[(128 + k) * 128 + (j - 128)];
        wt1a[i] = f2bf(v);
        float v2 = (j < 128) ? w2_1[k * 128 + j] : w2_1[(128 + k) * 128 + (j - 128)];
        wt1b[i] = f2bf(v2);
        return;
    }
    i -= 32768;
    if (i < 16384) {
        int j = i >> 7, k = i & 127;
        wt2a[i] = f2bf(w1_2[k * 128 + j]);
        wt2b[i] = f2bf(w2_2[k * 128 + j]);
        return;
    }
    i -= 16384;
    if (i < 256) {
        b256_1[i] = (i < 128) ? b1_1[i] : 0.f;
        b256_2[i] = (i < 128) ? b2_1[i] : 0.f;
    }
}

// ---------------- MFMA GEMM: Y[M][NOUT](bf16) = Xb[M][128](bf16) @ Wt^T (+bias[*deg])(relu) ----
// Wt is [NOUT][128] (transposed weights). Block = 4 waves x 16 rows = 64 rows.
// Fragments (v_mfma_f32_16x16x32_bf16): A: row=l&15, k=(l>>4)*8+j; B: col=l&15, same k;
// D: col=l&15, row=(l>>4)*4+reg.
template <int NOUT, bool RELU, bool DEGBIAS>
__global__ __launch_bounds__(256) void mgemm_k(const ushort* __restrict__ Xb, const ushort* __restrict__ Wt,
                                               const float* __restrict__ bias, const int* __restrict__ rp,
                                               ushort* __restrict__ Y, int M) {
    int wave = threadIdx.x >> 6, lane = threadIdx.x & 63;
    int row0 = blockIdx.x * 64 + wave * 16;
    int lr = lane & 15, lg = lane >> 4;

    const ushort* xrow = Xb + (size_t)(row0 + lr) * 128 + lg * 8;
    bf16x8 a[4];
#pragma unroll
    for (int k = 0; k < 4; ++k) a[k] = *reinterpret_cast<const bf16x8*>(xrow + k * 32);

    float degf[4];
    if (DEGBIAS) {
#pragma unroll
        for (int r = 0; r < 4; ++r) {
            int gr = row0 + lg * 4 + r;
            degf[r] = (float)(rp[gr + 1] - rp[gr]);
        }
    }

    for (int n = 0; n < NOUT / 16; ++n) {
        const ushort* wrow = Wt + (size_t)(n * 16 + lr) * 128 + lg * 8;
        f32x4 acc = {0.f, 0.f, 0.f, 0.f};
#pragma unroll
        for (int k = 0; k < 4; ++k) {
            bf16x8 b = *reinterpret_cast<const bf16x8*>(wrow + k * 32);
            acc = __builtin_amdgcn_mfma_f32_16x16x32_bf16(a[k], b, acc, 0, 0, 0);
        }
        int c = n * 16 + lr;
        float bv = bias[c];
#pragma unroll
        for (int r = 0; r < 4; ++r) {
            float v = acc[r];
            v += DEGBIAS ? degf[r] * bv : bv;
            if (RELU) v = fmaxf(v, 0.f);
            Y[(size_t)(row0 + lg * 4 + r) * NOUT + c] = f2bf(v);
        }
    }
}

// ---------------- edge aggregation: Hagg[n] = sum relu(A[n] + B[src]) (bf16 in, bf16 out) ----
__global__ __launch_bounds__(256) void agg_k(const ushort* __restrict__ AB,
                                             const int* __restrict__ rp, const int* __restrict__ col,
                                             ushort* __restrict__ Hagg, int M) {
    int wave = threadIdx.x >> 6;
    int lane = threadIdx.x & 63;
    int n = blockIdx.x * 4 + wave;
    uint av = *reinterpret_cast<const uint*>(AB + (size_t)n * 256 + lane * 2);
    float a0 = bf2f(av), a1 = bf2f_hi(av);
    float s0 = 0.f, s1 = 0.f;
    int e0 = rp[n], e1 = rp[n + 1];
    for (int e = e0; e < e1; ++e) {
        int s = col[e];
        uint bv = *reinterpret_cast<const uint*>(AB + (size_t)s * 256 + 128 + lane * 2);
        s0 += fmaxf(a0 + bf2f(bv), 0.f);
        s1 += fmaxf(a1 + bf2f_hi(bv), 0.f);
    }
    uint o = (uint)f2bf(s0) | ((uint)f2bf(s1) << 16);
    *reinterpret_cast<uint*>(Hagg + (size_t)n * 128 + lane * 2) = o;
}

// ---------------- pooling (node-parallel, sorted batch, atomic flush at boundaries) ----------
__global__ __launch_bounds__(128) void pool_k(const ushort* __restrict__ H, const int* __restrict__ batch,
                                              float* __restrict__ psum, int M, int nblk) {
    int f = threadIdx.x;
    int chunk = (M + nblk - 1) / nblk;
    int n0 = blockIdx.x * chunk;
    int n1 = n0 + chunk;
    if (n1 > M) n1 = M;
    if (n0 >= n1) return;
    int g = batch[n0];
    float acc = 0.f;
    for (int n = n0; n < n1; ++n) {
        int bg = batch[n];
        if (bg != g) {
            atomicAdd(&psum[g * 128 + f], acc);
            acc = 0.f;
            g = bg;
        }
        acc += bf2f((uint)H[(size_t)n * 128 + f]);
    }
    atomicAdd(&psum[g * 128 + f], acc);
}

// ---------------- graph boundaries ----------------
__global__ void gstart_k(const int* __restrict__ batch, int N, int G, int* __restrict__ gs) {
    int t = threadIdx.x;
    if (t > G) return;
    int lo = 0, hi = N;
    while (lo < hi) {
        int mid = (lo + hi) >> 1;
        if (batch[mid] < t) lo = mid + 1;
        else hi = mid;
    }
    gs[t] = lo;
}

// ---------------- head MLP: relu((psum/cnt)@wm1+bm1)@wm2+bm2 -> out[64][512] (fp32) ----------
__global__ __launch_bounds__(128) void head_k(const float* __restrict__ psum,
                                              const int* __restrict__ gs,
                                              const float* __restrict__ wm1, const float* __restrict__ bm1,
                                              const float* __restrict__ wm2, const float* __restrict__ bm2,
                                              float* __restrict__ out) {
    __shared__ float p[128];
    __shared__ float h[128];
    int g = blockIdx.x, t = threadIdx.x;
    int cnt = gs[g + 1] - gs[g];
    float rcp = 1.0f / (float)(cnt > 0 ? cnt : 1);
    p[t] = psum[g * 128 + t] * rcp;
    __syncthreads();
    float a = bm1[t];
    for (int k = 0; k < 128; ++k) a += p[k] * wm1[k * 128 + t];
    h[t] = fmaxf(a, 0.f);
    __syncthreads();
    float acc[4];
#pragma unroll
    for (int j = 0; j < 4; ++j) acc[j] = bm2[j * 128 + t];
    for (int k = 0; k < 128; ++k) {
        float hv = h[k];
#pragma unroll
        for (int j = 0; j < 4; ++j) acc[j] += hv * wm2[k * 512 + j * 128 + t];
    }
#pragma unroll
    for (int j = 0; j < 4; ++j) out[(size_t)g * 512 + j * 128 + t] = acc[j];
}

extern "C" void kernel_launch(void* const* d_in, const int* in_sizes, int n_in,
                              void* d_out, int out_size, void* d_ws, size_t ws_size,
                              hipStream_t stream) {
    const float* x = (const float*)d_in[0];
    const int* ei = (const int*)d_in[1];
    const int* batch = (const int*)d_in[2];
    const float* w1_1 = (const float*)d_in[3];
    const float* b1_1 = (const float*)d_in[4];
    const float* w1_2 = (const float*)d_in[5];
    const float* b1_2 = (const float*)d_in[6];
    const float* w2_1 = (const float*)d_in[7];
    const float* b2_1 = (const float*)d_in[8];
    const float* w2_2 = (const float*)d_in[9];
    const float* b2_2 = (const float*)d_in[10];
    const float* wm1 = (const float*)d_in[11];
    const float* bm1 = (const float*)d_in[12];
    const float* wm2 = (const float*)d_in[13];
    const float* bm2 = (const float*)d_in[14];

    const int E = in_sizes[1] / 2;
    const int M = in_sizes[0] / 128;
    const int* srcp = ei;
    const int* dstp = ei + E;

    char* ws = (char*)d_ws;
    size_t off = 0;
    auto alloc = [&](size_t bytes) -> void* {
        void* p = ws + off;
        off += (bytes + 255) & ~(size_t)255;
        return p;
    };
    ushort* AB = (ushort*)alloc((size_t)M * 256 * 2);    // [M][256] bf16: A|B
    ushort* Hagg = (ushort*)alloc((size_t)M * 128 * 2);  // [M][128] bf16
    ushort* H = (ushort*)alloc((size_t)M * 128 * 2);     // [M][128] bf16 layer output
    ushort* xb = (ushort*)alloc((size_t)M * 128 * 2);    // x cast to bf16
    int* rp = (int*)alloc((size_t)(M + 1) * 4);
    int* cursor = (int*)alloc((size_t)M * 4);
    int* col = (int*)alloc((size_t)E * 4);
    int* part = (int*)alloc(64 * 4);
    int* gs = (int*)alloc((GRAPHS + 1) * 4);
    float* psum = (float*)alloc(GRAPHS * 128 * 4);
    ushort* wt1a = (ushort*)alloc(256 * 128 * 2);
    ushort* wt1b = (ushort*)alloc(256 * 128 * 2);
    ushort* wt2a = (ushort*)alloc(128 * 128 * 2);
    ushort* wt2b = (ushort*)alloc(128 * 128 * 2);
    float* b256_1 = (float*)alloc(256 * 4);
    float* b256_2 = (float*)alloc(256 * 4);

    const int nb = (M + 1023) / 1024;

    // CSR build over dst (shared by both layers)
    zero_k<<<(M + 255) / 256, 256, 0, stream>>>(cursor, M);
    hist_k<<<(E + 255) / 256, 256, 0, stream>>>(dstp, cursor, E);
    scan1_k<<<nb, 256, 0, stream>>>(cursor, rp, part, M);
    scan2_k<<<1, 64, 0, stream>>>(part, nb);
    scan3_k<<<(M + 256) / 256, 256, 0, stream>>>(rp, cursor, part, M, nb);
    fill_k<<<(E + 255) / 256, 256, 0, stream>>>(srcp, dstp, cursor, col, E);

    // prep
    cast_k<<<(M * 32 + 255) / 256, 256, 0, stream>>>(x, xb, M * 32);
    prep_k<<<(32768 + 16384 + 256 + 255) / 256, 256, 0, stream>>>(
        w1_1, w2_1, w1_2, w2_2, b1_1, b2_1, wt1a, wt1b, wt2a, wt2b, b256_1, b256_2);

    // layer 1
    mgemm_k<256, false, false><<<M / 64, 256, 0, stream>>>(xb, wt1a, b256_1, nullptr, AB, M);
    agg_k<<<M / 4, 256, 0, stream>>>(AB, rp, col, Hagg, M);
    mgemm_k<128, true, true><<<M / 64, 256, 0, stream>>>(Hagg, wt2a, b1_2, rp, H, M);

    // layer 2
    mgemm_k<256, false, false><<<M / 64, 256, 0, stream>>>(H, wt1b, b256_2, nullptr, AB, M);
    agg_k<<<M / 4, 256, 0, stream>>>(AB, rp, col, Hagg, M);
    mgemm_k<128, true, true><<<M / 64, 256, 0, stream>>>(Hagg, wt2b, b2_2, rp, H, M);

    // pool + head
    zero_k<<<(GRAPHS * 128 + 255) / 256, 256, 0, stream>>>((int*)psum, GRAPHS * 128);
    gstart_k<<<1, 128, 0, stream>>>(batch, M, GRAPHS, gs);
    {
        const int nblk = 512;
        pool_k<<<nblk, 128, 0, stream>>>(H, batch, psum, M, nblk);
    }
    head_k<<<GRAPHS, 128, 0, stream>>>(psum, gs, wm1, bm1, wm2, bm2, (float*)d_out);
}

// Round 4
// 279.934 us; speedup vs baseline: 1.8991x; 1.2936x over previous
//
#include <hip/hip_runtime.h>
#include <cstdint>
#include <cstddef>

// GNNEncoder: 2x (edge-MLP GNN layer) + mean pool + MLP head. bf16 node pipeline.
//   AB = [A|B] = xb @ [W1a|W1b] + [b1|0]      (MFMA bf16 GEMM, bf16 out)
//   Hagg[n] = sum_{e: dst=n} relu(A[n] + B[src_e])   (bf16 gather, f32 accum)
//   H = relu(Hagg @ W2 + deg*b2)               (MFMA bf16 GEMM)

static constexpr int GRAPHS = 64;

using bf16x8 = __attribute__((ext_vector_type(8))) short;
using f32x4 = __attribute__((ext_vector_type(4))) float;

__device__ inline float bf2f(uint u) { return __builtin_bit_cast(float, u << 16); }
__device__ inline float bf2f_hi(uint u) { return __builtin_bit_cast(float, u & 0xffff0000u); }
__device__ inline ushort f2bf(float f) {
    uint u = __builtin_bit_cast(uint, f);
    return (ushort)((u + 0x7fffu + ((u >> 16) & 1u)) >> 16);
}

// ---------------- CSR build ----------------
__global__ __launch_bounds__(256) void zero_k(int* __restrict__ p, int n) {
    int i = blockIdx.x * 256 + threadIdx.x;
    if (i < n) p[i] = 0;
}

__global__ __launch_bounds__(256) void hist_k(const int* __restrict__ dst, int* __restrict__ deg, int E) {
    int i = blockIdx.x * 256 + threadIdx.x;
    if (i < E) atomicAdd(&deg[dst[i]], 1);
}

__global__ __launch_bounds__(256) void scan1_k(const int* __restrict__ deg, int* __restrict__ rp,
                                               int* __restrict__ part, int n) {
    __shared__ int ts[256];
    int b = blockIdx.x, t = threadIdx.x;
    int base = b * 1024 + t * 4;
    int v0 = (base + 0 < n) ? deg[base + 0] : 0;
    int v1 = (base + 1 < n) ? deg[base + 1] : 0;
    int v2 = (base + 2 < n) ? deg[base + 2] : 0;
    int v3 = (base + 3 < n) ? deg[base + 3] : 0;
    int l0 = v0, l1 = l0 + v1, l2 = l1 + v2, l3 = l2 + v3;
    ts[t] = l3;
    __syncthreads();
    for (int off = 1; off < 256; off <<= 1) {
        int x = (t >= off) ? ts[t - off] : 0;
        __syncthreads();
        ts[t] += x;
        __syncthreads();
    }
    int ex = ts[t] - l3;
    if (base + 0 < n) rp[base + 0] = ex;
    if (base + 1 < n) rp[base + 1] = ex + l0;
    if (base + 2 < n) rp[base + 2] = ex + l1;
    if (base + 3 < n) rp[base + 3] = ex + l2;
    if (t == 255) part[b] = ts[255];
}

__global__ void scan2_k(int* __restrict__ part, int nb) {
    if (threadIdx.x == 0 && blockIdx.x == 0) {
        int s = 0;
        for (int i = 0; i < nb; ++i) { int v = part[i]; part[i] = s; s += v; }
        part[nb] = s;
    }
}

__global__ __launch_bounds__(256) void scan3_k(int* __restrict__ rp, int* __restrict__ cursor,
                                               const int* __restrict__ part, int n, int nb) {
    int i = blockIdx.x * 256 + threadIdx.x;
    if (i < n) {
        int v = rp[i] + part[i >> 10];
        rp[i] = v;
        cursor[i] = v;
    } else if (i == n) {
        rp[n] = part[nb];
    }
}

__global__ __launch_bounds__(256) void fill_k(const int* __restrict__ src, const int* __restrict__ dst,
                                              int* __restrict__ cursor, int* __restrict__ col, int E) {
    int i = blockIdx.x * 256 + threadIdx.x;
    if (i < E) {
        int d = dst[i];
        int p = atomicAdd(&cursor[d], 1);
        col[p] = src[i];
    }
}

// ---------------- fused: x->bf16 cast (blocks 0..nc-1) + weight prep (blocks nc..) ----------
// wt1a[256][128]: wt1a[j][k] = j<128 ? w1_1[k][j] : w1_1[128+k][j-128]; wt1b from w2_1.
// wt2a[128][128] = w1_2^T; wt2b = w2_2^T. b256_1 = [b1_1|0], b256_2 = [b2_1|0].
__global__ __launch_bounds__(256) void prep_k(const float* __restrict__ x, ushort* __restrict__ xb, int n4,
                                              int nc,
                                              const float* __restrict__ w1_1, const float* __restrict__ w2_1,
                                              const float* __restrict__ w1_2, const float* __restrict__ w2_2,
                                              const float* __restrict__ b1_1, const float* __restrict__ b2_1,
                                              ushort* __restrict__ wt1a, ushort* __restrict__ wt1b,
                                              ushort* __restrict__ wt2a, ushort* __restrict__ wt2b,
                                              float* __restrict__ b256_1, float* __restrict__ b256_2) {
    int bb = blockIdx.x;
    if (bb < nc) {
        int i = bb * 256 + threadIdx.x;
        if (i >= n4) return;
        float4 v = *reinterpret_cast<const float4*>(x + (size_t)i * 4);
        ushort4 o;
        o.x = f2bf(v.x); o.y = f2bf(v.y); o.z = f2bf(v.z); o.w = f2bf(v.w);
        *reinterpret_cast<ushort4*>(xb + (size_t)i * 4) = o;
        return;
    }
    int i = (bb - nc) * 256 + threadIdx.x;
    if (i < 32768) {
        int j = i >> 7, k = i & 127;
        float v = (j < 128) ? w1_1[k * 128 + j] : w1_1[(128 + k) * 128 + (j - 128)];
        wt1a[i] = f2bf(v);
        float v2 = (j < 128) ? w2_1[k * 128 + j] : w2_1[(128 + k) * 128 + (j - 128)];
        wt1b[i] = f2bf(v2);
        return;
    }
    i -= 32768;
    if (i < 16384) {
        int j = i >> 7, k = i & 127;
        wt2a[i] = f2bf(w1_2[k * 128 + j]);
        wt2b[i] = f2bf(w2_2[k * 128 + j]);
        return;
    }
    i -= 16384;
    if (i < 256) {
        b256_1[i] = (i < 128) ? b1_1[i] : 0.f;
        b256_2[i] = (i < 128) ? b2_1[i] : 0.f;
    }
}

// ---------------- MFMA GEMM: Y[M][NOUT](bf16) = Xb[M][128](bf16) @ Wt^T (+bias[*deg])(relu) ----
template <int NOUT, bool RELU, bool DEGBIAS>
__global__ __launch_bounds__(256) void mgemm_k(const ushort* __restrict__ Xb, const ushort* __restrict__ Wt,
                                               const float* __restrict__ bias, const int* __restrict__ rp,
                                               ushort* __restrict__ Y, int M) {
    int wave = threadIdx.x >> 6, lane = threadIdx.x & 63;
    int row0 = blockIdx.x * 64 + wave * 16;
    int lr = lane & 15, lg = lane >> 4;

    const ushort* xrow = Xb + (size_t)(row0 + lr) * 128 + lg * 8;
    bf16x8 a[4];
#pragma unroll
    for (int k = 0; k < 4; ++k) a[k] = *reinterpret_cast<const bf16x8*>(xrow + k * 32);

    float degf[4];
    if (DEGBIAS) {
#pragma unroll
        for (int r = 0; r < 4; ++r) {
            int gr = row0 + lg * 4 + r;
            degf[r] = (float)(rp[gr + 1] - rp[gr]);
        }
    }

    for (int n = 0; n < NOUT / 16; ++n) {
        const ushort* wrow = Wt + (size_t)(n * 16 + lr) * 128 + lg * 8;
        f32x4 acc = {0.f, 0.f, 0.f, 0.f};
#pragma unroll
        for (int k = 0; k < 4; ++k) {
            bf16x8 b = *reinterpret_cast<const bf16x8*>(wrow + k * 32);
            acc = __builtin_amdgcn_mfma_f32_16x16x32_bf16(a[k], b, acc, 0, 0, 0);
        }
        int c = n * 16 + lr;
        float bv = bias[c];
#pragma unroll
        for (int r = 0; r < 4; ++r) {
            float v = acc[r];
            v += DEGBIAS ? degf[r] * bv : bv;
            if (RELU) v = fmaxf(v, 0.f);
            Y[(size_t)(row0 + lg * 4 + r) * NOUT + c] = f2bf(v);
        }
    }
}

// ---------------- edge aggregation: Hagg[n] = sum relu(A[n] + B[src]) --------------------
// One wave per node. 16 lanes per edge-row (16B/lane), 4 edge groups, 8 edges/iter via
// two independent gathers -> high memory-level parallelism. Cross-group reduce via shfl_xor.
__device__ inline void accum8(uint4 b, const float2* a, float2* acc) {
    const uint* bu = reinterpret_cast<const uint*>(&b);
#pragma unroll
    for (int j = 0; j < 4; ++j) {
        uint u = bu[j];
        acc[j].x += fmaxf(a[j].x + bf2f(u), 0.f);
        acc[j].y += fmaxf(a[j].y + bf2f_hi(u), 0.f);
    }
}

__global__ __launch_bounds__(256) void agg_k(const ushort* __restrict__ AB,
                                             const int* __restrict__ rp, const int* __restrict__ col,
                                             ushort* __restrict__ Hagg, int M) {
    int wave = threadIdx.x >> 6;
    int lane = threadIdx.x & 63;
    int n = blockIdx.x * 4 + wave;
    if (n >= M) return;
    int fs = lane & 15;   // feature slice (8 features = 16B)
    int lg = lane >> 4;   // edge group 0..3

    // A[n] slice (b1 already fused into A by mgemm bias)
    uint4 av = *reinterpret_cast<const uint4*>(AB + (size_t)n * 256 + fs * 8);
    float2 a[4];
    {
        const uint* au = reinterpret_cast<const uint*>(&av);
#pragma unroll
        for (int j = 0; j < 4; ++j) a[j] = make_float2(bf2f(au[j]), bf2f_hi(au[j]));
    }
    float2 acc[4] = {{0.f, 0.f}, {0.f, 0.f}, {0.f, 0.f}, {0.f, 0.f}};

    int e0 = rp[n], e1 = rp[n + 1];
    int deg = e1 - e0;
    int eMain = e0 + (deg & ~7);

    for (int eb = e0; eb < eMain; eb += 8) {
        int sA = col[eb + lg];
        int sB = col[eb + lg + 4];
        uint4 bA = *reinterpret_cast<const uint4*>(AB + (size_t)sA * 256 + 128 + fs * 8);
        uint4 bB = *reinterpret_cast<const uint4*>(AB + (size_t)sB * 256 + 128 + fs * 8);
        accum8(bA, a, acc);
        accum8(bB, a, acc);
    }
    for (int e = eMain + lg; e < e1; e += 4) {
        int s = col[e];
        uint4 b = *reinterpret_cast<const uint4*>(AB + (size_t)s * 256 + 128 + fs * 8);
        accum8(b, a, acc);
    }

    // reduce across the 4 edge groups (lanes l, l+16, l+32, l+48)
#pragma unroll
    for (int j = 0; j < 4; ++j) {
        acc[j].x += __shfl_xor(acc[j].x, 16);
        acc[j].y += __shfl_xor(acc[j].y, 16);
        acc[j].x += __shfl_xor(acc[j].x, 32);
        acc[j].y += __shfl_xor(acc[j].y, 32);
    }
    if (lg == 0) {
        uint4 o;
        uint* ou = reinterpret_cast<uint*>(&o);
#pragma unroll
        for (int j = 0; j < 4; ++j)
            ou[j] = (uint)f2bf(acc[j].x) | ((uint)f2bf(acc[j].y) << 16);
        *reinterpret_cast<uint4*>(Hagg + (size_t)n * 128 + fs * 8) = o;
    }
}

// ---------------- pooling (node-parallel, sorted batch, atomic flush at boundaries) ----------
__global__ __launch_bounds__(128) void pool_k(const ushort* __restrict__ H, const int* __restrict__ batch,
                                              float* __restrict__ psum, int M, int nblk) {
    int f = threadIdx.x;
    int chunk = (M + nblk - 1) / nblk;
    int n0 = blockIdx.x * chunk;
    int n1 = n0 + chunk;
    if (n1 > M) n1 = M;
    if (n0 >= n1) return;
    int g = batch[n0];
    float acc = 0.f;
    for (int n = n0; n < n1; ++n) {
        int bg = batch[n];
        if (bg != g) {
            atomicAdd(&psum[g * 128 + f], acc);
            acc = 0.f;
            g = bg;
        }
        acc += bf2f((uint)H[(size_t)n * 128 + f]);
    }
    atomicAdd(&psum[g * 128 + f], acc);
}

// ---------------- graph boundaries ----------------
__global__ void gstart_k(const int* __restrict__ batch, int N, int G, int* __restrict__ gs) {
    int t = threadIdx.x;
    if (t > G) return;
    int lo = 0, hi = N;
    while (lo < hi) {
        int mid = (lo + hi) >> 1;
        if (batch[mid] < t) lo = mid + 1;
        else hi = mid;
    }
    gs[t] = lo;
}

// ---------------- head MLP: relu((psum/cnt)@wm1+bm1)@wm2+bm2 -> out[64][512] (fp32) ----------
__global__ __launch_bounds__(128) void head_k(const float* __restrict__ psum,
                                              const int* __restrict__ gs,
                                              const float* __restrict__ wm1, const float* __restrict__ bm1,
                                              const float* __restrict__ wm2, const float* __restrict__ bm2,
                                              float* __restrict__ out) {
    __shared__ float p[128];
    __shared__ float h[128];
    int g = blockIdx.x, t = threadIdx.x;
    int cnt = gs[g + 1] - gs[g];
    float rcp = 1.0f / (float)(cnt > 0 ? cnt : 1);
    p[t] = psum[g * 128 + t] * rcp;
    __syncthreads();
    float a = bm1[t];
    for (int k = 0; k < 128; ++k) a += p[k] * wm1[k * 128 + t];
    h[t] = fmaxf(a, 0.f);
    __syncthreads();
    float acc[4];
#pragma unroll
    for (int j = 0; j < 4; ++j) acc[j] = bm2[j * 128 + t];
    for (int k = 0; k < 128; ++k) {
        float hv = h[k];
#pragma unroll
        for (int j = 0; j < 4; ++j) acc[j] += hv * wm2[k * 512 + j * 128 + t];
    }
#pragma unroll
    for (int j = 0; j < 4; ++j) out[(size_t)g * 512 + j * 128 + t] = acc[j];
}

extern "C" void kernel_launch(void* const* d_in, const int* in_sizes, int n_in,
                              void* d_out, int out_size, void* d_ws, size_t ws_size,
                              hipStream_t stream) {
    const float* x = (const float*)d_in[0];
    const int* ei = (const int*)d_in[1];
    const int* batch = (const int*)d_in[2];
    const float* w1_1 = (const float*)d_in[3];
    const float* b1_1 = (const float*)d_in[4];
    const float* w1_2 = (const float*)d_in[5];
    const float* b1_2 = (const float*)d_in[6];
    const float* w2_1 = (const float*)d_in[7];
    const float* b2_1 = (const float*)d_in[8];
    const float* w2_2 = (const float*)d_in[9];
    const float* b2_2 = (const float*)d_in[10];
    const float* wm1 = (const float*)d_in[11];
    const float* bm1 = (const float*)d_in[12];
    const float* wm2 = (const float*)d_in[13];
    const float* bm2 = (const float*)d_in[14];

    const int E = in_sizes[1] / 2;
    const int M = in_sizes[0] / 128;
    const int* srcp = ei;
    const int* dstp = ei + E;

    char* ws = (char*)d_ws;
    size_t off = 0;
    auto alloc = [&](size_t bytes) -> void* {
        void* p = ws + off;
        off += (bytes + 255) & ~(size_t)255;
        return p;
    };
    ushort* AB = (ushort*)alloc((size_t)M * 256 * 2);
    ushort* Hagg = (ushort*)alloc((size_t)M * 128 * 2);
    ushort* H = (ushort*)alloc((size_t)M * 128 * 2);
    ushort* xb = (ushort*)alloc((size_t)M * 128 * 2);
    int* rp = (int*)alloc((size_t)(M + 1) * 4);
    int* cursor = (int*)alloc((size_t)M * 4);
    int* col = (int*)alloc((size_t)E * 4);
    int* part = (int*)alloc(64 * 4);
    int* gs = (int*)alloc((GRAPHS + 1) * 4);
    float* psum = (float*)alloc(GRAPHS * 128 * 4);
    ushort* wt1a = (ushort*)alloc(256 * 128 * 2);
    ushort* wt1b = (ushort*)alloc(256 * 128 * 2);
    ushort* wt2a = (ushort*)alloc(128 * 128 * 2);
    ushort* wt2b = (ushort*)alloc(128 * 128 * 2);
    float* b256_1 = (float*)alloc(256 * 4);
    float* b256_2 = (float*)alloc(256 * 4);

    const int nb = (M + 1023) / 1024;

    // CSR build over dst (shared by both layers)
    zero_k<<<(M + 255) / 256, 256, 0, stream>>>(cursor, M);
    hist_k<<<(E + 255) / 256, 256, 0, stream>>>(dstp, cursor, E);
    scan1_k<<<nb, 256, 0, stream>>>(cursor, rp, part, M);
    scan2_k<<<1, 64, 0, stream>>>(part, nb);
    scan3_k<<<(M + 256) / 256, 256, 0, stream>>>(rp, cursor, part, M, nb);
    fill_k<<<(E + 255) / 256, 256, 0, stream>>>(srcp, dstp, cursor, col, E);

    // fused cast + weight prep
    {
        int n4 = M * 32;
        int nc = (n4 + 255) / 256;
        int np = (32768 + 16384 + 256 + 255) / 256;
        prep_k<<<nc + np, 256, 0, stream>>>(x, xb, n4, nc, w1_1, w2_1, w1_2, w2_2, b1_1, b2_1,
                                            wt1a, wt1b, wt2a, wt2b, b256_1, b256_2);
    }

    // layer 1
    mgemm_k<256, false, false><<<M / 64, 256, 0, stream>>>(xb, wt1a, b256_1, nullptr, AB, M);
    agg_k<<<(M + 3) / 4, 256, 0, stream>>>(AB, rp, col, Hagg, M);
    mgemm_k<128, true, true><<<M / 64, 256, 0, stream>>>(Hagg, wt2a, b1_2, rp, H, M);

    // layer 2
    mgemm_k<256, false, false><<<M / 64, 256, 0, stream>>>(H, wt1b, b256_2, nullptr, AB, M);
    agg_k<<<(M + 3) / 4, 256, 0, stream>>>(AB, rp, col, Hagg, M);
    mgemm_k<128, true, true><<<M / 64, 256, 0, stream>>>(Hagg, wt2b, b2_2, rp, H, M);

    // pool + head
    zero_k<<<(GRAPHS * 128 + 255) / 256, 256, 0, stream>>>((int*)psum, GRAPHS * 128);
    gstart_k<<<1, 128, 0, stream>>>(batch, M, GRAPHS, gs);
    {
        const int nblk = 512;
        pool_k<<<nblk, 128, 0, stream>>>(H, batch, psum, M, nblk);
    }
    head_k<<<GRAPHS, 128, 0, stream>>>(psum, gs, wm1, bm1, wm2, bm2, (float*)d_out);
}